// Round 1
// baseline (153.476 us; speedup 1.0000x reference)
//
#include <hip/hip_runtime.h>

typedef unsigned short u16;
typedef unsigned int u32;
typedef short bf8 __attribute__((ext_vector_type(8)));   // 8 bf16 = 4 VGPR (MFMA A/B frag)
typedef float f4v __attribute__((ext_vector_type(4)));   // 16x16 C/D frag
typedef float f16v __attribute__((ext_vector_type(16))); // 32x32 C/D frag

#define STR 72   // bf16 LDS row stride (144 B): 16B-aligned rows, 2-way (free) bank pattern

__device__ __forceinline__ u32 f2bf(float f){
    union{float f;u32 i;}c; c.f=f; u32 i=c.i;
    return (i + 0x7FFFu + ((i>>16)&1u)) >> 16;  // RNE
}

// stage 16 fp32 (row n, cols c0..c0+15) -> bf16 LDS row-major
__device__ __forceinline__ void stage_row16(const float* __restrict__ g, short* __restrict__ dst,
                                            int n, int c0){
    const float4* p = (const float4*)(g + n*64 + c0);
    float4 a=p[0], b=p[1], c=p[2], d=p[3];
    uint4 o0, o1;
    o0.x = f2bf(a.x)|(f2bf(a.y)<<16); o0.y = f2bf(a.z)|(f2bf(a.w)<<16);
    o0.z = f2bf(b.x)|(f2bf(b.y)<<16); o0.w = f2bf(b.z)|(f2bf(b.w)<<16);
    o1.x = f2bf(c.x)|(f2bf(c.y)<<16); o1.y = f2bf(c.z)|(f2bf(c.w)<<16);
    o1.z = f2bf(d.x)|(f2bf(d.y)<<16); o1.w = f2bf(d.z)|(f2bf(d.w)<<16);
    *(uint4*)&dst[n*STR + c0]     = o0;
    *(uint4*)&dst[n*STR + c0 + 8] = o1;
}

// 64x64x64 tile-row matmul: A-frags preloaded (wave's 16-row stripe), B read
// straight from GLOBAL bf16 [64][64] row-major (L2/L1-hot, 8 KB broadcast).
__device__ __forceinline__ void mmgB(const u16* __restrict__ Wt, bf8 a0, bf8 a1,
                                     int l15, int quad, f4v c[4]){
    #pragma unroll
    for (int nt=0; nt<4; ++nt){
        bf8 b0 = *(const bf8*)&Wt[(16*nt + l15)*64 + quad*8];
        bf8 b1 = *(const bf8*)&Wt[(16*nt + l15)*64 + 32 + quad*8];
        c[nt] = __builtin_amdgcn_mfma_f32_16x16x32_bf16(a0, b0, c[nt], 0,0,0);
        c[nt] = __builtin_amdgcn_mfma_f32_16x16x32_bf16(a1, b1, c[nt], 0,0,0);
    }
}

// ================= precompute kernel: batch-invariant prep only (4 blocks) =================
__global__ __launch_bounds__(256) void pre_kernel(
    const int* __restrict__ embed_id,
    const float* __restrict__ Wq, const float* __restrict__ Wk, const float* __restrict__ oW,
    const float* __restrict__ embeds, const float* __restrict__ sW, const float* __restrict__ sb,
    const float* __restrict__ strength,
    float* __restrict__ ws_s64, u16* __restrict__ ws_wq, u16* __restrict__ ws_wk,
    u16* __restrict__ ws_ow, u16* __restrict__ ws_e)
{
    const int j = blockIdx.x;
    const int t = threadIdx.x;

    if (j < 3) {
        // transpose W[64 in][64 out] fp32 -> bf16 [out][in], stride 64
        const float* W = (j==0) ? Wq : (j==1) ? Wk : oW;
        u16* dst = (j==0) ? ws_wq : (j==1) ? ws_wk : ws_ow;
        const int kp = t >> 3, ng = t & 7;
        const float4* r0 = (const float4*)(W + (2*kp  )*64 + 8*ng);
        const float4* r1 = (const float4*)(W + (2*kp+1)*64 + 8*ng);
        float4 a0=r0[0], a1=r0[1], b0=r1[0], b1=r1[1];
        float lo[8]={a0.x,a0.y,a0.z,a0.w,a1.x,a1.y,a1.z,a1.w};
        float hi[8]={b0.x,b0.y,b0.z,b0.w,b1.x,b1.y,b1.z,b1.w};
        #pragma unroll
        for (int i=0;i<8;++i)
            *(u32*)&dst[(8*ng+i)*64 + 2*kp] = f2bf(lo[i]) | (f2bf(hi[i])<<16);
    } else {
        // E = embeds[id] -> bf16 row-major; s64 = strength @ str_W + str_b
        __shared__ float sp[4][64];
        {
            const int n = t >> 2, c0 = (t & 3) << 4;
            const float4* p = (const float4*)(embeds + (size_t)(*embed_id)*4096 + n*64 + c0);
            float4 a=p[0], b=p[1], c=p[2], d=p[3];
            uint4 o0, o1;
            o0.x = f2bf(a.x)|(f2bf(a.y)<<16); o0.y = f2bf(a.z)|(f2bf(a.w)<<16);
            o0.z = f2bf(b.x)|(f2bf(b.y)<<16); o0.w = f2bf(b.z)|(f2bf(b.w)<<16);
            o1.x = f2bf(c.x)|(f2bf(c.y)<<16); o1.y = f2bf(c.z)|(f2bf(c.w)<<16);
            o1.z = f2bf(d.x)|(f2bf(d.y)<<16); o1.w = f2bf(d.z)|(f2bf(d.w)<<16);
            *(uint4*)&ws_e[n*64 + c0]     = o0;
            *(uint4*)&ws_e[n*64 + c0 + 8] = o1;
        }
        {
            const int d = t & 63, part = t >> 6;
            const float* wp = sW + part*128*64 + d;
            const float* s  = strength + part*128;
            float acc = 0.f;
            #pragma unroll 8
            for (int i = 0; i < 128; ++i) acc = fmaf(s[i], wp[i*64], acc);
            sp[part][d] = acc;
        }
        __syncthreads();
        if (t < 64) ws_s64[t] = sp[0][t] + sp[1][t] + sp[2][t] + sp[3][t] + sb[t];
    }
}

// ================= main kernel =================
__global__ __launch_bounds__(256, 3) void attn_main_kernel(
    const float* __restrict__ x, const float* __restrict__ pos,
    const float* __restrict__ gate, const float* __restrict__ ob,
    const float* __restrict__ pW1, const float* __restrict__ pb1,
    const float* __restrict__ pW2, const float* __restrict__ pb2,
    const float* __restrict__ hW,
    const float* __restrict__ ws_s64,
    const u16* __restrict__ ws_wq, const u16* __restrict__ ws_wk,
    const u16* __restrict__ ws_ow, const u16* __restrict__ ws_e,
    float* __restrict__ out)
{
    // 5 x 9216 B + 1 KiB = 47104 B -> 3 blocks/CU (was 2)
    __shared__ short B0[64*STR];  // xbf -> P(head0)
    __shared__ short B1[64*STR];  // P(head1)
    __shared__ short B2[64*STR];  // qbf -> P(head2)
    __shared__ short B3[64*STR];  // kbf -> P(head3) -> ctx
    __shared__ short VT[64*STR];  // V^T
    __shared__ float pat_l[4][64]; // g * softmax_k(-t[h][k])

    const int t    = threadIdx.x;
    const int b    = blockIdx.x;
    const int lane = t & 63;
    const int w    = t >> 6;        // wave id = head id
    const int l15  = lane & 15;
    const int l31  = lane & 31;
    const int l5   = lane >> 5;
    const int quad = lane >> 4;
    const int n    = t >> 2;        // staging row (wave w stages its own rows 16w..16w+15)
    const int c0   = (t & 3) << 4;  // staging col base

    // ---- P0: stage x (wave-own rows, no barrier needed); fused pos MLP+softmax (wave-local) ----
    stage_row16(x + (size_t)b*4096, B0, n, c0);

    float g = 1.f/(1.f + __expf(-gate[w]));
    {
        // pos attention is rank-1 in q: softmax_k(t[h][q]-t[h][k]+hb) = softmax_k(-t[h][k]).
        // Each wave computes its own head's 64-vector; write/read of pat_l[w] is same-wave.
        const float4 pv = *(const float4*)(pos + ((size_t)b*64 + lane)*4);
        float h1[4], p8[8];
        #pragma unroll
        for (int jj = 0; jj < 4; ++jj){
            float a = pb1[jj];
            a = fmaf(pv.x, pW1[0*4+jj], a);
            a = fmaf(pv.y, pW1[1*4+jj], a);
            a = fmaf(pv.z, pW1[2*4+jj], a);
            a = fmaf(pv.w, pW1[3*4+jj], a);
            h1[jj] = fmaxf(a, 0.f);
        }
        #pragma unroll
        for (int f = 0; f < 8; ++f){
            float a = pb2[f];
            #pragma unroll
            for (int jj = 0; jj < 4; ++jj) a = fmaf(h1[jj], pW2[jj*8+f], a);
            p8[f] = a;
        }
        float tv = 0.f;
        #pragma unroll
        for (int f = 0; f < 8; ++f) tv = fmaf(p8[f], hW[f*4+w], tv);
        float v0 = -tv;
        float m = v0;
        #pragma unroll
        for (int off = 32; off; off >>= 1) m = fmaxf(m, __shfl_xor(m, off));
        float e = __expf(v0 - m);
        float ssum = e;
        #pragma unroll
        for (int off = 32; off; off >>= 1) ssum += __shfl_xor(ssum, off);
        pat_l[w][lane] = g * (e / ssum);
    }

    float svv[4];
    #pragma unroll
    for (int nt=0;nt<4;++nt) svv[nt] = ws_s64[16*nt + l15];
    float obv[4];
    #pragma unroll
    for (int nt=0;nt<4;++nt) obv[nt] = ob[16*nt + l15];

    asm volatile("" ::: "memory");  // compiler fence: LDS stage stores precede same-wave frag reads

    // ---- P1+P2: q,k,v from x (A-frags shared); weights read from global (L2-hot) ----
    {
        bf8 xa0 = *(const bf8*)&B0[(16*w + l15)*STR + quad*8];
        bf8 xa1 = *(const bf8*)&B0[(16*w + l15)*STR + 32 + quad*8];
        f4v cq[4], ck[4], cv[4];
        #pragma unroll
        for (int nt=0;nt<4;++nt){
            cq[nt][0]=0.f;cq[nt][1]=0.f;cq[nt][2]=0.f;cq[nt][3]=0.f;
            ck[nt][0]=0.f;ck[nt][1]=0.f;ck[nt][2]=0.f;ck[nt][3]=0.f;
            cv[nt][0]=0.f;cv[nt][1]=0.f;cv[nt][2]=0.f;cv[nt][3]=0.f;
        }
        mmgB(ws_wq, xa0, xa1, l15, quad, cq);
        mmgB(ws_wk, xa0, xa1, l15, quad, ck);
        mmgB(ws_e,  xa0, xa1, l15, quad, cv);   // B = E row-major == (E^T)^T
        #pragma unroll
        for (int nt=0;nt<4;++nt)
            #pragma unroll
            for (int r=0;r<4;++r){
                B2[(16*w + quad*4 + r)*STR + 16*nt + l15] = (short)f2bf(0.25f*cq[nt][r]);
                B3[(16*w + quad*4 + r)*STR + 16*nt + l15] = (short)f2bf(ck[nt][r]);
            }
        #pragma unroll
        for (int nt=0;nt<4;++nt){
            float sv = svv[nt];
            uint2 pk;
            pk.x = f2bf(cv[nt][0]+sv) | (f2bf(cv[nt][1]+sv)<<16);
            pk.y = f2bf(cv[nt][2]+sv) | (f2bf(cv[nt][3]+sv)<<16);
            *(uint2*)&VT[(16*nt + l15)*STR + 16*w + quad*4] = pk;   // VT[d][krow]
        }
    }
    __syncthreads();   // SYNC1: q,k,V^T visible; all x/B0 reads done

    // ---- P4: S^T = K@Q^T (32x32x16); softmax + gate-mix in C/D layout ----
    f16v S[2][2];
    {
        bf8 ka0 = *(const bf8*)&B3[(     l31)*STR + 16*w + 8*l5];
        bf8 ka1 = *(const bf8*)&B3[(32 + l31)*STR + 16*w + 8*l5];
        bf8 qb0 = *(const bf8*)&B2[(     l31)*STR + 16*w + 8*l5];
        bf8 qb1 = *(const bf8*)&B2[(32 + l31)*STR + 16*w + 8*l5];
        #pragma unroll
        for (int mt=0;mt<2;++mt)
            #pragma unroll
            for (int nt=0;nt<2;++nt)
                #pragma unroll
                for (int i=0;i<16;++i) S[mt][nt][i] = 0.f;
        S[0][0] = __builtin_amdgcn_mfma_f32_32x32x16_bf16(ka0, qb0, S[0][0], 0,0,0);
        S[0][1] = __builtin_amdgcn_mfma_f32_32x32x16_bf16(ka0, qb1, S[0][1], 0,0,0);
        S[1][0] = __builtin_amdgcn_mfma_f32_32x32x16_bf16(ka1, qb0, S[1][0], 0,0,0);
        S[1][1] = __builtin_amdgcn_mfma_f32_32x32x16_bf16(ka1, qb1, S[1][1], 0,0,0);
    }
    float inv_[2];
    #pragma unroll
    for (int nt=0;nt<2;++nt){   // two q columns per lane
        float m = S[0][nt][0];
        #pragma unroll
        for (int i=1;i<16;++i) m = fmaxf(m, S[0][nt][i]);
        #pragma unroll
        for (int i=0;i<16;++i) m = fmaxf(m, S[1][nt][i]);
        m = fmaxf(m, __shfl_xor(m, 32));
        float l = 0.f;
        #pragma unroll
        for (int mt=0;mt<2;++mt)
            #pragma unroll
            for (int i=0;i<16;++i){ float e = __expf(S[mt][nt][i]-m); S[mt][nt][i] = e; l += e; }
        l += __shfl_xor(l, 32);
        float c1 = (1.f - g) / l;
        float tot = 0.f;
        #pragma unroll
        for (int mt=0;mt<2;++mt)
            #pragma unroll
            for (int rg=0;rg<4;++rg){
                // pat_l already has g folded in; broadcast reads (conflict-free)
                const float4 tv = *(const float4*)&pat_l[w][32*mt + 8*rg + 4*l5];
                float a0 = fmaf(c1, S[mt][nt][rg*4+0], tv.x);
                float a1 = fmaf(c1, S[mt][nt][rg*4+1], tv.y);
                float a2 = fmaf(c1, S[mt][nt][rg*4+2], tv.z);
                float a3 = fmaf(c1, S[mt][nt][rg*4+3], tv.w);
                S[mt][nt][rg*4+0]=a0; S[mt][nt][rg*4+1]=a1;
                S[mt][nt][rg*4+2]=a2; S[mt][nt][rg*4+3]=a3;
                tot += a0+a1+a2+a3;
            }
        tot += __shfl_xor(tot, 32);
        inv_[nt] = 1.f / tot;
    }
    __syncthreads();   // SYNC2: all S^T frag reads of B2/B3 + P2's B0 reads done before P overwrites

    // ---- P5: P writeback row-major to per-head buffer ----
    short* Pb = (w==0) ? B0 : (w==1) ? B1 : (w==2) ? B2 : B3;
    #pragma unroll
    for (int nt=0;nt<2;++nt)
        #pragma unroll
        for (int mt=0;mt<2;++mt)
            #pragma unroll
            for (int rg=0;rg<4;++rg){
                float v0 = S[mt][nt][rg*4+0]*inv_[nt], v1 = S[mt][nt][rg*4+1]*inv_[nt];
                float v2 = S[mt][nt][rg*4+2]*inv_[nt], v3 = S[mt][nt][rg*4+3]*inv_[nt];
                uint2 pk;
                pk.x = f2bf(v0) | (f2bf(v1)<<16);
                pk.y = f2bf(v2) | (f2bf(v3)<<16);
                *(uint2*)&Pb[(32*nt + l31)*STR + 32*mt + 8*rg + 4*l5] = pk;
            }
    asm volatile("" ::: "memory");  // same-wave P write -> P read ordering (no barrier needed)

    // ---- P6: O_h = P_h @ V_h (16x16x32) ----
    f4v o[4];
    {
        bf8 bv0 = *(const bf8*)&VT[(16*w + l15)*STR + quad*8];
        bf8 bv1 = *(const bf8*)&VT[(16*w + l15)*STR + 32 + quad*8];
        #pragma unroll
        for (int mt=0;mt<4;++mt){
            o[mt][0]=0.f;o[mt][1]=0.f;o[mt][2]=0.f;o[mt][3]=0.f;
            bf8 a0 = *(const bf8*)&Pb[(16*mt + l15)*STR + quad*8];
            bf8 a1 = *(const bf8*)&Pb[(16*mt + l15)*STR + 32 + quad*8];
            o[mt] = __builtin_amdgcn_mfma_f32_16x16x32_bf16(a0, bv0, o[mt], 0,0,0);
            o[mt] = __builtin_amdgcn_mfma_f32_16x16x32_bf16(a1, bv1, o[mt], 0,0,0);
        }
    }
    __syncthreads();   // SYNC3: all P6 reads done before ctx overwrites B3

    // ---- P7: ctx -> B3 row-major ----
    #pragma unroll
    for (int mt=0;mt<4;++mt)
        #pragma unroll
        for (int r=0;r<4;++r)
            B3[(16*mt + quad*4 + r)*STR + 16*w + l15] = (short)f2bf(o[mt][r]);
    __syncthreads();   // SYNC4: ctx visible cross-wave

    // ---- P8: out = ctx@oW + ob -> global (oW B-frags from L2-hot global) ----
    {
        bf8 ca0 = *(const bf8*)&B3[(16*w + l15)*STR + quad*8];
        bf8 ca1 = *(const bf8*)&B3[(16*w + l15)*STR + 32 + quad*8];
        f4v c[4];
        #pragma unroll
        for (int nt=0;nt<4;++nt){
            c[nt][0]=obv[nt];c[nt][1]=obv[nt];c[nt][2]=obv[nt];c[nt][3]=obv[nt];
        }
        mmgB(ws_ow, ca0, ca1, l15, quad, c);
        #pragma unroll
        for (int nt=0;nt<4;++nt)
            #pragma unroll
            for (int r=0;r<4;++r)
                out[((size_t)b*64 + 16*w + quad*4 + r)*64 + 16*nt + l15] = c[nt][r];
    }
}

extern "C" void kernel_launch(void* const* d_in, const int* in_sizes, int n_in,
                              void* d_out, int out_size, void* d_ws, size_t ws_size,
                              hipStream_t stream) {
    const int B = in_sizes[0] / (64 * 64);  // 2048

    // workspace carve (33 KB): s64 | WqT | WkT | oWT | E (bf16)
    float* ws_s64 = (float*)d_ws;
    u16*   ws_wq  = (u16*)(ws_s64 + 64);
    u16*   ws_wk  = ws_wq + 4096;
    u16*   ws_ow  = ws_wk + 4096;
    u16*   ws_e   = ws_ow + 4096;

    pre_kernel<<<4, 256, 0, stream>>>(
        (const int*)d_in[3],
        (const float*)d_in[4],  (const float*)d_in[5],  (const float*)d_in[14],
        (const float*)d_in[13], (const float*)d_in[16], (const float*)d_in[17],
        (const float*)d_in[2],
        ws_s64, ws_wq, ws_wk, ws_ow, ws_e);

    attn_main_kernel<<<B, 256, 0, stream>>>(
        (const float*)d_in[0],  (const float*)d_in[1],
        (const float*)d_in[12], (const float*)d_in[15],
        (const float*)d_in[6],  (const float*)d_in[7],  (const float*)d_in[8],  (const float*)d_in[9],
        (const float*)d_in[10],
        ws_s64, ws_wq, ws_wk, ws_ow, ws_e,
        (float*)d_out);
}

// Round 2
// 138.120 us; speedup vs baseline: 1.1112x; 1.1112x over previous
//
#include <hip/hip_runtime.h>

typedef unsigned short u16;
typedef unsigned int u32;
typedef short bf8 __attribute__((ext_vector_type(8)));   // 8 bf16 = 4 VGPR (MFMA A/B frag)
typedef float f4v __attribute__((ext_vector_type(4)));   // 16x16 C/D frag
typedef float f16v __attribute__((ext_vector_type(16))); // 32x32 C/D frag

#define STR 72   // bf16 LDS row stride (144 B): 16B-aligned rows, 2-way (free) bank pattern

__device__ __forceinline__ u32 f2bf(float f){
    union{float f;u32 i;}c; c.f=f; u32 i=c.i;
    return (i + 0x7FFFu + ((i>>16)&1u)) >> 16;  // RNE
}

// stage 16 fp32 (row n, cols c0..c0+15) -> bf16 LDS row-major
__device__ __forceinline__ void stage_row16(const float* __restrict__ g, short* __restrict__ dst,
                                            int n, int c0){
    const float4* p = (const float4*)(g + n*64 + c0);
    float4 a=p[0], b=p[1], c=p[2], d=p[3];
    uint4 o0, o1;
    o0.x = f2bf(a.x)|(f2bf(a.y)<<16); o0.y = f2bf(a.z)|(f2bf(a.w)<<16);
    o0.z = f2bf(b.x)|(f2bf(b.y)<<16); o0.w = f2bf(b.z)|(f2bf(b.w)<<16);
    o1.x = f2bf(c.x)|(f2bf(c.y)<<16); o1.y = f2bf(c.z)|(f2bf(c.w)<<16);
    o1.z = f2bf(d.x)|(f2bf(d.y)<<16); o1.w = f2bf(d.z)|(f2bf(d.w)<<16);
    *(uint4*)&dst[n*STR + c0]     = o0;
    *(uint4*)&dst[n*STR + c0 + 8] = o1;
}

// ================= precompute kernel: batch-invariant prep only (4 blocks) =================
__global__ __launch_bounds__(256) void pre_kernel(
    const int* __restrict__ embed_id,
    const float* __restrict__ Wq, const float* __restrict__ Wk, const float* __restrict__ oW,
    const float* __restrict__ embeds, const float* __restrict__ sW, const float* __restrict__ sb,
    const float* __restrict__ strength,
    float* __restrict__ ws_s64, u16* __restrict__ ws_wq, u16* __restrict__ ws_wk,
    u16* __restrict__ ws_ow, u16* __restrict__ ws_e)
{
    const int j = blockIdx.x;
    const int t = threadIdx.x;

    if (j < 3) {
        // transpose W[64 in][64 out] fp32 -> bf16 [out][in], stride 64.
        // Wq gets the 1/sqrt(dh)=0.25 q-scale folded in (exact: power of 2).
        const float* W = (j==0) ? Wq : (j==1) ? Wk : oW;
        u16* dst = (j==0) ? ws_wq : (j==1) ? ws_wk : ws_ow;
        const float scl = (j==0) ? 0.25f : 1.0f;
        const int kp = t >> 3, ng = t & 7;
        const float4* r0 = (const float4*)(W + (2*kp  )*64 + 8*ng);
        const float4* r1 = (const float4*)(W + (2*kp+1)*64 + 8*ng);
        float4 a0=r0[0], a1=r0[1], b0=r1[0], b1=r1[1];
        float lo[8]={a0.x,a0.y,a0.z,a0.w,a1.x,a1.y,a1.z,a1.w};
        float hi[8]={b0.x,b0.y,b0.z,b0.w,b1.x,b1.y,b1.z,b1.w};
        #pragma unroll
        for (int i=0;i<8;++i)
            *(u32*)&dst[(8*ng+i)*64 + 2*kp] = f2bf(scl*lo[i]) | (f2bf(scl*hi[i])<<16);
    } else {
        // E = embeds[id] -> bf16 row-major; s64 = strength @ str_W + str_b
        __shared__ float sp[4][64];
        {
            const int n = t >> 2, c0 = (t & 3) << 4;
            const float4* p = (const float4*)(embeds + (size_t)(*embed_id)*4096 + n*64 + c0);
            float4 a=p[0], b=p[1], c=p[2], d=p[3];
            uint4 o0, o1;
            o0.x = f2bf(a.x)|(f2bf(a.y)<<16); o0.y = f2bf(a.z)|(f2bf(a.w)<<16);
            o0.z = f2bf(b.x)|(f2bf(b.y)<<16); o0.w = f2bf(b.z)|(f2bf(b.w)<<16);
            o1.x = f2bf(c.x)|(f2bf(c.y)<<16); o1.y = f2bf(c.z)|(f2bf(c.w)<<16);
            o1.z = f2bf(d.x)|(f2bf(d.y)<<16); o1.w = f2bf(d.z)|(f2bf(d.w)<<16);
            *(uint4*)&ws_e[n*64 + c0]     = o0;
            *(uint4*)&ws_e[n*64 + c0 + 8] = o1;
        }
        {
            const int d = t & 63, part = t >> 6;
            const float* wp = sW + part*128*64 + d;
            const float* s  = strength + part*128;
            float acc = 0.f;
            #pragma unroll 8
            for (int i = 0; i < 128; ++i) acc = fmaf(s[i], wp[i*64], acc);
            sp[part][d] = acc;
        }
        __syncthreads();
        if (t < 64) ws_s64[t] = sp[0][t] + sp[1][t] + sp[2][t] + sp[3][t] + sb[t];
    }
}

// ================= main kernel =================
// Wave w owns output COLUMNS 16w..16w+15 of every 64x64 matmul. Consequences:
//  - per-matrix B-frag = 2 x bf8 = 8 VGPR -> all 4 weight matrices preloaded in
//    the prologue (32 VGPR), zero global loads inside compute phases;
//  - q/k/v cols 16w == head-w contraction dims -> P1->P4 is wave-local, no barrier.
__global__ __launch_bounds__(256, 3) void attn_main_kernel(
    const float* __restrict__ x, const float* __restrict__ pos,
    const float* __restrict__ gate, const float* __restrict__ ob,
    const float* __restrict__ pW1, const float* __restrict__ pb1,
    const float* __restrict__ pW2, const float* __restrict__ pb2,
    const float* __restrict__ hW,
    const float* __restrict__ ws_s64,
    const u16* __restrict__ ws_wq, const u16* __restrict__ ws_wk,
    const u16* __restrict__ ws_ow, const u16* __restrict__ ws_e,
    float* __restrict__ out)
{
    // 5 x 9216 B + 1 KiB = 47104 B -> 3 blocks/CU
    __shared__ short B0[64*STR];  // xbf -> P(head0)
    __shared__ short PX[64*STR];  // P(head1)
    __shared__ short B2[64*STR];  // qbf -> P(head2)
    __shared__ short B3[64*STR];  // kbf -> P(head3) -> ctx
    __shared__ short VT[64*STR];  // V^T
    __shared__ float pat_l[4][64]; // g * softmax_k(-t[h][k])

    const int t    = threadIdx.x;
    const int b    = blockIdx.x;
    const int lane = t & 63;
    const int w    = t >> 6;        // wave id = head id = output col-stripe
    const int l15  = lane & 15;
    const int l31  = lane & 31;
    const int l5   = lane >> 5;
    const int quad = lane >> 4;
    const int n    = t >> 2;        // staging row
    const int c0   = (t & 3) << 4;  // staging col base

    // ---- prologue: preload per-wave weight B-frags (col-stripe 16w..16w+15) ----
    const int wq_off = (16*w + l15)*64 + quad*8;
    bf8 bq0 = *(const bf8*)&ws_wq[wq_off];
    bf8 bq1 = *(const bf8*)&ws_wq[wq_off + 32];
    bf8 bk0 = *(const bf8*)&ws_wk[wq_off];
    bf8 bk1 = *(const bf8*)&ws_wk[wq_off + 32];
    bf8 be0 = *(const bf8*)&ws_e [wq_off];
    bf8 be1 = *(const bf8*)&ws_e [wq_off + 32];
    bf8 bo0 = *(const bf8*)&ws_ow[wq_off];
    bf8 bo1 = *(const bf8*)&ws_ow[wq_off + 32];
    const float sv  = ws_s64[16*w + l15];   // v-bias for this lane's column
    const float obv = ob[16*w + l15];       // out-bias for this lane's column

    // ---- P0: stage x -> B0 (bf16); fused pos MLP + softmax (wave-local) ----
    stage_row16(x + (size_t)b*4096, B0, n, c0);

    float g = 1.f/(1.f + __expf(-gate[w]));
    {
        // pos attention is rank-1 in q: softmax_k(t[h][q]-t[h][k]+hb) = softmax_k(-t[h][k])
        const float4 pv = *(const float4*)(pos + ((size_t)b*64 + lane)*4);
        float h1[4], p8[8];
        #pragma unroll
        for (int jj = 0; jj < 4; ++jj){
            float a = pb1[jj];
            a = fmaf(pv.x, pW1[0*4+jj], a);
            a = fmaf(pv.y, pW1[1*4+jj], a);
            a = fmaf(pv.z, pW1[2*4+jj], a);
            a = fmaf(pv.w, pW1[3*4+jj], a);
            h1[jj] = fmaxf(a, 0.f);
        }
        #pragma unroll
        for (int f = 0; f < 8; ++f){
            float a = pb2[f];
            #pragma unroll
            for (int jj = 0; jj < 4; ++jj) a = fmaf(h1[jj], pW2[jj*8+f], a);
            p8[f] = a;
        }
        float tv = 0.f;
        #pragma unroll
        for (int f = 0; f < 8; ++f) tv = fmaf(p8[f], hW[f*4+w], tv);
        float v0 = -tv;
        float m = v0;
        #pragma unroll
        for (int off = 32; off; off >>= 1) m = fmaxf(m, __shfl_xor(m, off));
        float e = __expf(v0 - m);
        float ssum = e;
        #pragma unroll
        for (int off = 32; off; off >>= 1) ssum += __shfl_xor(ssum, off);
        pat_l[w][lane] = g * (e / ssum);
    }
    __syncthreads();   // SYNC0: x visible (A-frags span all waves' staged rows)

    // ---- P1: q,k,v (col-stripe per wave, weights in regs; wave-local results) ----
    #pragma unroll
    for (int mt=0; mt<4; ++mt){
        bf8 a0 = *(const bf8*)&B0[(16*mt + l15)*STR + quad*8];
        bf8 a1 = *(const bf8*)&B0[(16*mt + l15)*STR + 32 + quad*8];
        f4v cq, ck, cv;
        #pragma unroll
        for (int r=0;r<4;++r){ cq[r]=0.f; ck[r]=0.f; cv[r]=sv; }
        cq = __builtin_amdgcn_mfma_f32_16x16x32_bf16(a0, bq0, cq, 0,0,0);
        cq = __builtin_amdgcn_mfma_f32_16x16x32_bf16(a1, bq1, cq, 0,0,0);
        ck = __builtin_amdgcn_mfma_f32_16x16x32_bf16(a0, bk0, ck, 0,0,0);
        ck = __builtin_amdgcn_mfma_f32_16x16x32_bf16(a1, bk1, ck, 0,0,0);
        cv = __builtin_amdgcn_mfma_f32_16x16x32_bf16(a0, be0, cv, 0,0,0);
        cv = __builtin_amdgcn_mfma_f32_16x16x32_bf16(a1, be1, cv, 0,0,0);
        #pragma unroll
        for (int r=0;r<4;++r){
            B2[(16*mt + quad*4 + r)*STR + 16*w + l15] = (short)f2bf(cq[r]);
            B3[(16*mt + quad*4 + r)*STR + 16*w + l15] = (short)f2bf(ck[r]);
        }
        uint2 pk;
        pk.x = f2bf(cv[0]) | (f2bf(cv[1])<<16);
        pk.y = f2bf(cv[2]) | (f2bf(cv[3])<<16);
        *(uint2*)&VT[(16*w + l15)*STR + 16*mt + quad*4] = pk;   // VT[d][n], wave-own rows
    }
    asm volatile("" ::: "memory");  // same-wave LDS write->read ordering (P1 -> P4)

    // ---- P4: S^T = K@Q^T (32x32x16); softmax + gate-mix in C/D layout ----
    // Contraction dims for head w are exactly cols 16w..16w+15 -> wave-local, no barrier.
    f16v S[2][2];
    {
        bf8 ka0 = *(const bf8*)&B3[(     l31)*STR + 16*w + 8*l5];
        bf8 ka1 = *(const bf8*)&B3[(32 + l31)*STR + 16*w + 8*l5];
        bf8 qb0 = *(const bf8*)&B2[(     l31)*STR + 16*w + 8*l5];
        bf8 qb1 = *(const bf8*)&B2[(32 + l31)*STR + 16*w + 8*l5];
        #pragma unroll
        for (int mt=0;mt<2;++mt)
            #pragma unroll
            for (int nt=0;nt<2;++nt)
                #pragma unroll
                for (int i=0;i<16;++i) S[mt][nt][i] = 0.f;
        S[0][0] = __builtin_amdgcn_mfma_f32_32x32x16_bf16(ka0, qb0, S[0][0], 0,0,0);
        S[0][1] = __builtin_amdgcn_mfma_f32_32x32x16_bf16(ka0, qb1, S[0][1], 0,0,0);
        S[1][0] = __builtin_amdgcn_mfma_f32_32x32x16_bf16(ka1, qb0, S[1][0], 0,0,0);
        S[1][1] = __builtin_amdgcn_mfma_f32_32x32x16_bf16(ka1, qb1, S[1][1], 0,0,0);
    }
    float inv_[2];
    #pragma unroll
    for (int nt=0;nt<2;++nt){   // two q columns per lane
        float m = S[0][nt][0];
        #pragma unroll
        for (int i=1;i<16;++i) m = fmaxf(m, S[0][nt][i]);
        #pragma unroll
        for (int i=0;i<16;++i) m = fmaxf(m, S[1][nt][i]);
        m = fmaxf(m, __shfl_xor(m, 32));
        float l = 0.f;
        #pragma unroll
        for (int mt=0;mt<2;++mt)
            #pragma unroll
            for (int i=0;i<16;++i){ float e = __expf(S[mt][nt][i]-m); S[mt][nt][i] = e; l += e; }
        l += __shfl_xor(l, 32);
        float c1 = (1.f - g) / l;
        float tot = 0.f;
        #pragma unroll
        for (int mt=0;mt<2;++mt)
            #pragma unroll
            for (int rg=0;rg<4;++rg){
                const float4 tv = *(const float4*)&pat_l[w][32*mt + 8*rg + 4*l5];
                float a0 = fmaf(c1, S[mt][nt][rg*4+0], tv.x);
                float a1 = fmaf(c1, S[mt][nt][rg*4+1], tv.y);
                float a2 = fmaf(c1, S[mt][nt][rg*4+2], tv.z);
                float a3 = fmaf(c1, S[mt][nt][rg*4+3], tv.w);
                S[mt][nt][rg*4+0]=a0; S[mt][nt][rg*4+1]=a1;
                S[mt][nt][rg*4+2]=a2; S[mt][nt][rg*4+3]=a3;
                tot += a0+a1+a2+a3;
            }
        tot += __shfl_xor(tot, 32);
        inv_[nt] = 1.f / tot;
    }
    __syncthreads();   // SYNC2: all P4 frag reads of B0/B2/B3 done before P overwrites

    // ---- P5: P writeback row-major to per-head buffer ----
    short* Pb = (w==0) ? B0 : (w==1) ? PX : (w==2) ? B2 : B3;
    #pragma unroll
    for (int nt=0;nt<2;++nt)
        #pragma unroll
        for (int mt=0;mt<2;++mt)
            #pragma unroll
            for (int rg=0;rg<4;++rg){
                float v0 = S[mt][nt][rg*4+0]*inv_[nt], v1 = S[mt][nt][rg*4+1]*inv_[nt];
                float v2 = S[mt][nt][rg*4+2]*inv_[nt], v3 = S[mt][nt][rg*4+3]*inv_[nt];
                uint2 pk;
                pk.x = f2bf(v0) | (f2bf(v1)<<16);
                pk.y = f2bf(v2) | (f2bf(v3)<<16);
                *(uint2*)&Pb[(32*nt + l31)*STR + 32*mt + 8*rg + 4*l5] = pk;
            }
    asm volatile("" ::: "memory");  // same-wave P write -> P read ordering

    // ---- P6: O_h = P_h @ V_h (16x16x32); V^T rows are wave-own ----
    f4v o[4];
    {
        bf8 bv0 = *(const bf8*)&VT[(16*w + l15)*STR + quad*8];
        bf8 bv1 = *(const bf8*)&VT[(16*w + l15)*STR + 32 + quad*8];
        #pragma unroll
        for (int mt=0;mt<4;++mt){
            o[mt][0]=0.f;o[mt][1]=0.f;o[mt][2]=0.f;o[mt][3]=0.f;
            bf8 a0 = *(const bf8*)&Pb[(16*mt + l15)*STR + quad*8];
            bf8 a1 = *(const bf8*)&Pb[(16*mt + l15)*STR + 32 + quad*8];
            o[mt] = __builtin_amdgcn_mfma_f32_16x16x32_bf16(a0, bv0, o[mt], 0,0,0);
            o[mt] = __builtin_amdgcn_mfma_f32_16x16x32_bf16(a1, bv1, o[mt], 0,0,0);
        }
    }
    __syncthreads();   // SYNC3: all P6 reads done before ctx overwrites B3

    // ---- P7: ctx -> B3 row-major (wave w writes its d-cols 16w..16w+15) ----
    #pragma unroll
    for (int mt=0;mt<4;++mt)
        #pragma unroll
        for (int r=0;r<4;++r)
            B3[(16*mt + quad*4 + r)*STR + 16*w + l15] = (short)f2bf(o[mt][r]);
    __syncthreads();   // SYNC4: ctx visible cross-wave

    // ---- P8: out = ctx@oW + ob -> global (oW B-frags in regs) ----
    #pragma unroll
    for (int mt=0;mt<4;++mt){
        bf8 ca0 = *(const bf8*)&B3[(16*mt + l15)*STR + quad*8];
        bf8 ca1 = *(const bf8*)&B3[(16*mt + l15)*STR + 32 + quad*8];
        f4v c;
        #pragma unroll
        for (int r=0;r<4;++r) c[r] = obv;
        c = __builtin_amdgcn_mfma_f32_16x16x32_bf16(ca0, bo0, c, 0,0,0);
        c = __builtin_amdgcn_mfma_f32_16x16x32_bf16(ca1, bo1, c, 0,0,0);
        #pragma unroll
        for (int r=0;r<4;++r)
            out[((size_t)b*64 + 16*mt + quad*4 + r)*64 + 16*w + l15] = c[r];
    }
}

extern "C" void kernel_launch(void* const* d_in, const int* in_sizes, int n_in,
                              void* d_out, int out_size, void* d_ws, size_t ws_size,
                              hipStream_t stream) {
    const int B = in_sizes[0] / (64 * 64);  // 2048

    // workspace carve (33 KB): s64 | WqT | WkT | oWT | E (bf16)
    float* ws_s64 = (float*)d_ws;
    u16*   ws_wq  = (u16*)(ws_s64 + 64);
    u16*   ws_wk  = ws_wq + 4096;
    u16*   ws_ow  = ws_wk + 4096;
    u16*   ws_e   = ws_ow + 4096;

    pre_kernel<<<4, 256, 0, stream>>>(
        (const int*)d_in[3],
        (const float*)d_in[4],  (const float*)d_in[5],  (const float*)d_in[14],
        (const float*)d_in[13], (const float*)d_in[16], (const float*)d_in[17],
        (const float*)d_in[2],
        ws_s64, ws_wq, ws_wk, ws_ow, ws_e);

    attn_main_kernel<<<B, 256, 0, stream>>>(
        (const float*)d_in[0],  (const float*)d_in[1],
        (const float*)d_in[12], (const float*)d_in[15],
        (const float*)d_in[6],  (const float*)d_in[7],  (const float*)d_in[8],  (const float*)d_in[9],
        (const float*)d_in[10],
        ws_s64, ws_wq, ws_wk, ws_ow, ws_e,
        (float*)d_out);
}